// Round 1
// baseline (949.594 us; speedup 1.0000x reference)
//
#include <hip/hip_runtime.h>
#include <cstddef>

// Problem constants (from reference setup_inputs)
static constexpr int NN   = 100000;   // nodes
static constexpr int NE   = 3200000;  // edges
static constexpr int CIN  = 512;
static constexpr int CHID = 40;
static constexpr int COUT = 20;

// ---------------- CSR build ----------------

__global__ __launch_bounds__(256) void k_count(const int* __restrict__ dst, int* __restrict__ cnt, int n_edges) {
  const int e = blockIdx.x * 256 + threadIdx.x;
  if (e < n_edges) atomicAdd(&cnt[dst[e]], 1);
}

// block of 256 scans 1024 elements; writes per-element exclusive scan (within block),
// block totals, and fused dinv = rsqrt(deg) = rsqrt(cnt+1).
__global__ __launch_bounds__(256) void k_scanA(const int* __restrict__ cnt, int* __restrict__ excl,
                                               int* __restrict__ bsums, float* __restrict__ dinv, int n) {
  __shared__ int sdata[256];
  const int t = threadIdx.x;
  const int base = blockIdx.x * 1024 + t * 4;
  int v[4];
#pragma unroll
  for (int j = 0; j < 4; ++j) {
    const int i = base + j;
    v[j] = (i < n) ? cnt[i] : 0;
    if (i < n) dinv[i] = rsqrtf((float)(v[j] + 1));
  }
  const int s4 = v[0] + v[1] + v[2] + v[3];
  sdata[t] = s4;
  __syncthreads();
  for (int off = 1; off < 256; off <<= 1) {
    int val = 0;
    if (t >= off) val = sdata[t - off];
    __syncthreads();
    sdata[t] += val;
    __syncthreads();
  }
  int run = sdata[t] - s4;  // exclusive prefix of this thread's 4 items
#pragma unroll
  for (int j = 0; j < 4; ++j) {
    const int i = base + j;
    if (i < n) excl[i] = run;
    run += v[j];
  }
  if (t == 255) bsums[blockIdx.x] = sdata[255];
}

__global__ __launch_bounds__(256) void k_scanB(int* __restrict__ bsums, int nb) {
  __shared__ int sdata[256];
  const int t = threadIdx.x;
  const int v = (t < nb) ? bsums[t] : 0;
  sdata[t] = v;
  __syncthreads();
  for (int off = 1; off < 256; off <<= 1) {
    int val = 0;
    if (t >= off) val = sdata[t - off];
    __syncthreads();
    sdata[t] += val;
    __syncthreads();
  }
  if (t < nb) bsums[t] = sdata[t] - v;  // exclusive, in place
}

__global__ __launch_bounds__(256) void k_scanC(int* __restrict__ rowptr, int* __restrict__ rowcur,
                                               const int* __restrict__ boff, int n, int n_edges) {
  const int i = blockIdx.x * 256 + threadIdx.x;
  if (i < n) {
    const int v = rowptr[i] + boff[i >> 10];
    rowptr[i] = v;
    rowcur[i] = v;
  }
  if (i == 0) rowptr[n] = n_edges;
}

__global__ __launch_bounds__(256) void k_fill(const int* __restrict__ src, const int* __restrict__ dst,
                                              const float* __restrict__ dinv, int* __restrict__ rowcur,
                                              int* __restrict__ csr_src, float* __restrict__ csr_w, int n_edges) {
  const int e = blockIdx.x * 256 + threadIdx.x;
  if (e >= n_edges) return;
  const int s = src[e];
  const int d = dst[e];
  const int pos = atomicAdd(&rowcur[d], 1);
  csr_src[pos] = s;
  csr_w[pos] = dinv[s] * dinv[d];  // symmetric norm, precomputed per edge
}

// ---------------- GEMMs (fp32 vector; W indices wave-uniform -> s_load) ----------------

__global__ __launch_bounds__(256) void k_gemm1(const float* __restrict__ x, const float* __restrict__ W,
                                               float* __restrict__ h, int n) {
  const int node = blockIdx.x * 256 + threadIdx.x;
  if (node >= n) return;
  const float4* __restrict__ x4 = (const float4*)(x + (size_t)node * CIN);
  float acc[CHID];
#pragma unroll
  for (int c = 0; c < CHID; ++c) acc[c] = 0.f;
  for (int kk = 0; kk < CIN / 4; ++kk) {
    const float4 xv = x4[kk];
    const float* __restrict__ Wk = W + kk * 4 * CHID;
#pragma unroll
    for (int c = 0; c < CHID; ++c) {
      float a = acc[c];
      a = fmaf(xv.x, Wk[c], a);
      a = fmaf(xv.y, Wk[CHID + c], a);
      a = fmaf(xv.z, Wk[2 * CHID + c], a);
      a = fmaf(xv.w, Wk[3 * CHID + c], a);
      acc[c] = a;
    }
  }
  float* __restrict__ o = h + (size_t)node * CHID;
#pragma unroll
  for (int c = 0; c < CHID; ++c) o[c] = acc[c];
}

__global__ __launch_bounds__(256) void k_gemm2(const float* __restrict__ t1, const float* __restrict__ W,
                                               float* __restrict__ g, int n) {
  const int node = blockIdx.x * 256 + threadIdx.x;
  if (node >= n) return;
  const float4* __restrict__ r4 = (const float4*)(t1 + (size_t)node * CHID);
  float acc[COUT];
#pragma unroll
  for (int c = 0; c < COUT; ++c) acc[c] = 0.f;
#pragma unroll
  for (int kk = 0; kk < CHID / 4; ++kk) {
    const float4 xv = r4[kk];
    const float* __restrict__ Wk = W + kk * 4 * COUT;
#pragma unroll
    for (int c = 0; c < COUT; ++c) {
      float a = acc[c];
      a = fmaf(xv.x, Wk[c], a);
      a = fmaf(xv.y, Wk[COUT + c], a);
      a = fmaf(xv.z, Wk[2 * COUT + c], a);
      a = fmaf(xv.w, Wk[3 * COUT + c], a);
      acc[c] = a;
    }
  }
  float* __restrict__ o = g + (size_t)node * COUT;
#pragma unroll
  for (int c = 0; c < COUT; ++c) o[c] = acc[c];
}

// ---------------- CSR aggregation: one wave per node, lanes = channels ----------------

template <int CH, bool RELU>
__global__ __launch_bounds__(256) void k_agg(const float* __restrict__ h, const int* __restrict__ rowptr,
                                             const int* __restrict__ csr_src, const float* __restrict__ csr_w,
                                             const float* __restrict__ dinv, const float* __restrict__ bias,
                                             float* __restrict__ out, int n) {
  const int wid = (blockIdx.x * 256 + (int)threadIdx.x) >> 6;
  const int lane = threadIdx.x & 63;
  if (wid >= n) return;
  const int node = __builtin_amdgcn_readfirstlane(wid);  // wave-uniform -> scalar loads below
  const int r0 = rowptr[node];
  const int r1 = rowptr[node + 1];
  const float dv = dinv[node];
  const float self_w = dv * dv;  // self-loop norm = 1/deg
  const bool act = lane < CH;
  float acc = 0.f;
  if (act) acc = h[(size_t)node * CH + lane] * self_w;
  int i = r0;
  for (; i + 4 <= r1; i += 4) {
    const int s0 = csr_src[i + 0];
    const int s1 = csr_src[i + 1];
    const int s2 = csr_src[i + 2];
    const int s3 = csr_src[i + 3];
    const float w0 = csr_w[i + 0];
    const float w1 = csr_w[i + 1];
    const float w2 = csr_w[i + 2];
    const float w3 = csr_w[i + 3];
    if (act) {
      const float g0 = h[(size_t)s0 * CH + lane];
      const float g1 = h[(size_t)s1 * CH + lane];
      const float g2 = h[(size_t)s2 * CH + lane];
      const float g3 = h[(size_t)s3 * CH + lane];
      acc = fmaf(g0, w0, acc);
      acc = fmaf(g1, w1, acc);
      acc = fmaf(g2, w2, acc);
      acc = fmaf(g3, w3, acc);
    }
  }
  for (; i < r1; ++i) {
    const int s = csr_src[i];
    const float w = csr_w[i];
    if (act) acc = fmaf(h[(size_t)s * CH + lane], w, acc);
  }
  if (act) {
    float v = acc + bias[lane];
    if (RELU) v = fmaxf(v, 0.f);
    out[(size_t)node * CH + lane] = v;
  }
}

// ---------------- launch ----------------

extern "C" void kernel_launch(void* const* d_in, const int* in_sizes, int n_in,
                              void* d_out, int out_size, void* d_ws, size_t ws_size,
                              hipStream_t stream) {
  const float* x   = (const float*)d_in[0];
  const int*   ei  = (const int*)d_in[1];
  const float* W1  = (const float*)d_in[2];
  const float* b1  = (const float*)d_in[3];
  const float* W2  = (const float*)d_in[4];
  const float* b2  = (const float*)d_in[5];
  float* out = (float*)d_out;

  const int* srcp = ei;        // edge_index[0]
  const int* dstp = ei + NE;   // edge_index[1]

  // workspace layout (~60 MB)
  char* ws = (char*)d_ws;
  size_t off = 0;
  auto take = [&](size_t bytes) -> char* {
    char* p = ws + off;
    off = (off + bytes + 255) & ~(size_t)255;
    return p;
  };
  int*   cnt     = (int*)take((size_t)NN * 4);
  int*   rowptr  = (int*)take((size_t)(NN + 1) * 4);
  int*   rowcur  = (int*)take((size_t)NN * 4);
  float* dinv    = (float*)take((size_t)NN * 4);
  int*   bsums   = (int*)take(256 * 4);
  int*   csr_src = (int*)take((size_t)NE * 4);
  float* csr_w   = (float*)take((size_t)NE * 4);
  float* h1      = (float*)take((size_t)NN * CHID * 4);
  float* t1      = (float*)take((size_t)NN * CHID * 4);
  float* g2      = h1;  // h1 dead after agg1; reuse for layer-2 GEMM output

  (void)in_sizes; (void)n_in; (void)out_size; (void)ws_size;

  hipMemsetAsync(cnt, 0, (size_t)NN * 4, stream);

  k_count<<<(NE + 255) / 256, 256, 0, stream>>>(dstp, cnt, NE);
  const int nb = (NN + 1023) / 1024;  // 98
  k_scanA<<<nb, 256, 0, stream>>>(cnt, rowptr, bsums, dinv, NN);
  k_scanB<<<1, 256, 0, stream>>>(bsums, nb);
  k_scanC<<<(NN + 255) / 256, 256, 0, stream>>>(rowptr, rowcur, bsums, NN, NE);
  k_fill<<<(NE + 255) / 256, 256, 0, stream>>>(srcp, dstp, dinv, rowcur, csr_src, csr_w, NE);

  k_gemm1<<<(NN + 255) / 256, 256, 0, stream>>>(x, W1, h1, NN);
  k_agg<CHID, true><<<(NN + 3) / 4, 256, 0, stream>>>(h1, rowptr, csr_src, csr_w, dinv, b1, t1, NN);
  k_gemm2<<<(NN + 255) / 256, 256, 0, stream>>>(t1, W2, g2, NN);
  k_agg<COUT, false><<<(NN + 3) / 4, 256, 0, stream>>>(g2, rowptr, csr_src, csr_w, dinv, b2, out, NN);
}

// Round 2
// 832.386 us; speedup vs baseline: 1.1408x; 1.1408x over previous
//
#include <hip/hip_runtime.h>
#include <cstddef>

// Problem constants (from reference setup_inputs)
static constexpr int NN   = 100000;   // nodes
static constexpr int NE   = 3200000;  // edges
static constexpr int CIN  = 512;
static constexpr int CHID = 40;
static constexpr int COUT = 20;

// ---------------- CSR build ----------------

// count in-degree AND record each edge's rank within its dst bucket (coalesced write).
__global__ __launch_bounds__(256) void k_count(const int* __restrict__ dst, int* __restrict__ cnt,
                                               int* __restrict__ rank, int n_edges) {
  const int e = blockIdx.x * 256 + threadIdx.x;
  if (e < n_edges) rank[e] = atomicAdd(&cnt[dst[e]], 1);
}

// block of 256 scans 1024 elements; writes per-element exclusive scan (within block),
// block totals, and fused dinv = rsqrt(deg) = rsqrt(cnt+1).
__global__ __launch_bounds__(256) void k_scanA(const int* __restrict__ cnt, int* __restrict__ excl,
                                               int* __restrict__ bsums, float* __restrict__ dinv, int n) {
  __shared__ int sdata[256];
  const int t = threadIdx.x;
  const int base = blockIdx.x * 1024 + t * 4;
  int v[4];
#pragma unroll
  for (int j = 0; j < 4; ++j) {
    const int i = base + j;
    v[j] = (i < n) ? cnt[i] : 0;
    if (i < n) dinv[i] = rsqrtf((float)(v[j] + 1));
  }
  const int s4 = v[0] + v[1] + v[2] + v[3];
  sdata[t] = s4;
  __syncthreads();
  for (int off = 1; off < 256; off <<= 1) {
    int val = 0;
    if (t >= off) val = sdata[t - off];
    __syncthreads();
    sdata[t] += val;
    __syncthreads();
  }
  int run = sdata[t] - s4;  // exclusive prefix of this thread's 4 items
#pragma unroll
  for (int j = 0; j < 4; ++j) {
    const int i = base + j;
    if (i < n) excl[i] = run;
    run += v[j];
  }
  if (t == 255) bsums[blockIdx.x] = sdata[255];
}

__global__ __launch_bounds__(256) void k_scanB(int* __restrict__ bsums, int nb) {
  __shared__ int sdata[256];
  const int t = threadIdx.x;
  const int v = (t < nb) ? bsums[t] : 0;
  sdata[t] = v;
  __syncthreads();
  for (int off = 1; off < 256; off <<= 1) {
    int val = 0;
    if (t >= off) val = sdata[t - off];
    __syncthreads();
    sdata[t] += val;
    __syncthreads();
  }
  if (t < nb) bsums[t] = sdata[t] - v;  // exclusive, in place
}

__global__ __launch_bounds__(256) void k_scanC(int* __restrict__ rowptr, const int* __restrict__ boff,
                                               int n, int n_edges) {
  const int i = blockIdx.x * 256 + threadIdx.x;
  if (i < n) rowptr[i] += boff[i >> 10];
  if (i == 0) rowptr[n] = n_edges;
}

// pure gather + single scattered 4B write per edge (no atomics here).
__global__ __launch_bounds__(256) void k_fill(const int* __restrict__ src, const int* __restrict__ dst,
                                              const int* __restrict__ rank, const int* __restrict__ rowptr,
                                              int* __restrict__ csr_src, int n_edges) {
  const int e = blockIdx.x * 256 + threadIdx.x;
  if (e >= n_edges) return;
  const int d = dst[e];
  const int pos = rowptr[d] + rank[e];
  csr_src[pos] = src[e];
}

// ---------------- GEMMs (fp32 vector; W indices wave-uniform -> s_load) ----------------

__global__ __launch_bounds__(256) void k_gemm1(const float* __restrict__ x, const float* __restrict__ W,
                                               float* __restrict__ h, int n) {
  const int node = blockIdx.x * 256 + threadIdx.x;
  if (node >= n) return;
  const float4* __restrict__ x4 = (const float4*)(x + (size_t)node * CIN);
  float acc[CHID];
#pragma unroll
  for (int c = 0; c < CHID; ++c) acc[c] = 0.f;
  for (int kk = 0; kk < CIN / 4; ++kk) {
    const float4 xv = x4[kk];
    const float* __restrict__ Wk = W + kk * 4 * CHID;
#pragma unroll
    for (int c = 0; c < CHID; ++c) {
      float a = acc[c];
      a = fmaf(xv.x, Wk[c], a);
      a = fmaf(xv.y, Wk[CHID + c], a);
      a = fmaf(xv.z, Wk[2 * CHID + c], a);
      a = fmaf(xv.w, Wk[3 * CHID + c], a);
      acc[c] = a;
    }
  }
  float* __restrict__ o = h + (size_t)node * CHID;
#pragma unroll
  for (int c = 0; c < CHID; ++c) o[c] = acc[c];
}

__global__ __launch_bounds__(256) void k_gemm2(const float* __restrict__ t1, const float* __restrict__ W,
                                               float* __restrict__ g, int n) {
  const int node = blockIdx.x * 256 + threadIdx.x;
  if (node >= n) return;
  const float4* __restrict__ r4 = (const float4*)(t1 + (size_t)node * CHID);
  float acc[COUT];
#pragma unroll
  for (int c = 0; c < COUT; ++c) acc[c] = 0.f;
#pragma unroll
  for (int kk = 0; kk < CHID / 4; ++kk) {
    const float4 xv = r4[kk];
    const float* __restrict__ Wk = W + kk * 4 * COUT;
#pragma unroll
    for (int c = 0; c < COUT; ++c) {
      float a = acc[c];
      a = fmaf(xv.x, Wk[c], a);
      a = fmaf(xv.y, Wk[COUT + c], a);
      a = fmaf(xv.z, Wk[2 * COUT + c], a);
      a = fmaf(xv.w, Wk[3 * COUT + c], a);
      acc[c] = a;
    }
  }
  float* __restrict__ o = g + (size_t)node * COUT;
#pragma unroll
  for (int c = 0; c < COUT; ++c) o[c] = acc[c];
}

// ---------------- CSR aggregation ----------------
// Layer 1 (CH=40): one wave per node, lanes 0..39 = channels. csr_src + dinv
// loads are wave-uniform -> scalar load chain; weight computed on the fly.
__global__ __launch_bounds__(256) void k_agg40(const float* __restrict__ h, const int* __restrict__ rowptr,
                                               const int* __restrict__ csr_src, const float* __restrict__ dinv,
                                               const float* __restrict__ bias, float* __restrict__ out, int n) {
  const int wid = (blockIdx.x * 256 + (int)threadIdx.x) >> 6;
  const int lane = threadIdx.x & 63;
  if (wid >= n) return;
  const int node = __builtin_amdgcn_readfirstlane(wid);
  const int r0 = rowptr[node];
  const int r1 = rowptr[node + 1];
  const float dv = dinv[node];
  const float self_w = dv * dv;  // self-loop norm = 1/deg
  const bool act = lane < CHID;
  float acc = 0.f;
  if (act) acc = h[(size_t)node * CHID + lane] * self_w;
  int i = r0;
  for (; i + 4 <= r1; i += 4) {
    const int s0 = csr_src[i + 0];
    const int s1 = csr_src[i + 1];
    const int s2 = csr_src[i + 2];
    const int s3 = csr_src[i + 3];
    const float w0 = dinv[s0] * dv;
    const float w1 = dinv[s1] * dv;
    const float w2 = dinv[s2] * dv;
    const float w3 = dinv[s3] * dv;
    if (act) {
      const float g0 = h[(size_t)s0 * CHID + lane];
      const float g1 = h[(size_t)s1 * CHID + lane];
      const float g2 = h[(size_t)s2 * CHID + lane];
      const float g3 = h[(size_t)s3 * CHID + lane];
      acc = fmaf(g0, w0, acc);
      acc = fmaf(g1, w1, acc);
      acc = fmaf(g2, w2, acc);
      acc = fmaf(g3, w3, acc);
    }
  }
  for (; i < r1; ++i) {
    const int s = csr_src[i];
    const float w = dinv[s] * dv;
    if (act) acc = fmaf(h[(size_t)s * CHID + lane], w, acc);
  }
  if (act) {
    float v = acc + bias[lane];
    v = fmaxf(v, 0.f);  // ReLU (layer 1 only)
    out[(size_t)node * CHID + lane] = v;
  }
}

// Layer 2 (CH=20): 3 nodes per wave (lanes 0..59), per-lane loop with exec-mask
// divergence across the 3 subgroups; loads within a subgroup coalesce/broadcast.
__global__ __launch_bounds__(256) void k_agg20(const float* __restrict__ h, const int* __restrict__ rowptr,
                                               const int* __restrict__ csr_src, const float* __restrict__ dinv,
                                               const float* __restrict__ bias, float* __restrict__ out, int n) {
  const int wave = (blockIdx.x * 256 + (int)threadIdx.x) >> 6;
  const int lane = threadIdx.x & 63;
  const int sub = lane / COUT;   // 0..2 active, 3 => idle lanes 60..63
  const int ch = lane % COUT;
  const int node = wave * 3 + sub;
  if (sub >= 3 || node >= n) return;
  const int r0 = rowptr[node];
  const int r1 = rowptr[node + 1];
  const float dv = dinv[node];
  float acc = h[(size_t)node * COUT + ch] * (dv * dv);
  int i = r0;
  for (; i + 2 <= r1; i += 2) {
    const int s0 = csr_src[i + 0];
    const int s1 = csr_src[i + 1];
    const float w0 = dinv[s0] * dv;
    const float w1 = dinv[s1] * dv;
    acc = fmaf(h[(size_t)s0 * COUT + ch], w0, acc);
    acc = fmaf(h[(size_t)s1 * COUT + ch], w1, acc);
  }
  if (i < r1) {
    const int s = csr_src[i];
    acc = fmaf(h[(size_t)s * COUT + ch], dinv[s] * dv, acc);
  }
  out[(size_t)node * COUT + ch] = acc + bias[ch];
}

// ---------------- launch ----------------

extern "C" void kernel_launch(void* const* d_in, const int* in_sizes, int n_in,
                              void* d_out, int out_size, void* d_ws, size_t ws_size,
                              hipStream_t stream) {
  const float* x   = (const float*)d_in[0];
  const int*   ei  = (const int*)d_in[1];
  const float* W1  = (const float*)d_in[2];
  const float* b1  = (const float*)d_in[3];
  const float* W2  = (const float*)d_in[4];
  const float* b2  = (const float*)d_in[5];
  float* out = (float*)d_out;

  const int* srcp = ei;        // edge_index[0]
  const int* dstp = ei + NE;   // edge_index[1]

  // workspace layout (~59 MB)
  char* ws = (char*)d_ws;
  size_t off = 0;
  auto take = [&](size_t bytes) -> char* {
    char* p = ws + off;
    off = (off + bytes + 255) & ~(size_t)255;
    return p;
  };
  int*   cnt     = (int*)take((size_t)NN * 4);
  int*   rowptr  = (int*)take((size_t)(NN + 1) * 4);
  float* dinv    = (float*)take((size_t)NN * 4);
  int*   bsums   = (int*)take(256 * 4);
  int*   rank    = (int*)take((size_t)NE * 4);
  int*   csr_src = (int*)take((size_t)NE * 4);
  float* h1      = (float*)take((size_t)NN * CHID * 4);
  float* t1      = (float*)take((size_t)NN * CHID * 4);
  float* g2      = h1;  // h1 dead after agg1; reuse for layer-2 GEMM output

  (void)in_sizes; (void)n_in; (void)out_size; (void)ws_size;

  hipMemsetAsync(cnt, 0, (size_t)NN * 4, stream);

  k_count<<<(NE + 255) / 256, 256, 0, stream>>>(dstp, cnt, rank, NE);
  const int nb = (NN + 1023) / 1024;  // 98
  k_scanA<<<nb, 256, 0, stream>>>(cnt, rowptr, bsums, dinv, NN);
  k_scanB<<<1, 256, 0, stream>>>(bsums, nb);
  k_scanC<<<(NN + 255) / 256, 256, 0, stream>>>(rowptr, bsums, NN, NE);
  k_fill<<<(NE + 255) / 256, 256, 0, stream>>>(srcp, dstp, rank, rowptr, csr_src, NE);

  k_gemm1<<<(NN + 255) / 256, 256, 0, stream>>>(x, W1, h1, NN);
  k_agg40<<<(NN + 3) / 4, 256, 0, stream>>>(h1, rowptr, csr_src, dinv, b1, t1, NN);
  k_gemm2<<<(NN + 255) / 256, 256, 0, stream>>>(t1, W2, g2, NN);
  const int nwaves2 = (NN + 2) / 3;
  k_agg20<<<(nwaves2 + 3) / 4, 256, 0, stream>>>(g2, rowptr, csr_src, dinv, b2, out, NN);
}

// Round 4
// 817.811 us; speedup vs baseline: 1.1611x; 1.0178x over previous
//
#include <hip/hip_runtime.h>
#include <cstddef>

// Problem constants (from reference setup_inputs)
static constexpr int NN   = 100000;   // nodes
static constexpr int NE   = 3200000;  // edges
static constexpr int CIN  = 512;
static constexpr int CHID = 40;
static constexpr int COUT = 20;

// ---------------- CSR build ----------------

// count in-degree AND record each edge's rank within its dst bucket (coalesced write).
__global__ __launch_bounds__(256) void k_count(const int* __restrict__ dst, int* __restrict__ cnt,
                                               int* __restrict__ rank, int n_edges) {
  const int e = blockIdx.x * 256 + threadIdx.x;
  if (e < n_edges) rank[e] = atomicAdd(&cnt[dst[e]], 1);
}

// block of 256 scans 1024 elements; writes per-element exclusive scan (within block),
// block totals, and fused dinv = rsqrt(deg) = rsqrt(cnt+1).
__global__ __launch_bounds__(256) void k_scanA(const int* __restrict__ cnt, int* __restrict__ excl,
                                               int* __restrict__ bsums, float* __restrict__ dinv, int n) {
  __shared__ int sdata[256];
  const int t = threadIdx.x;
  const int base = blockIdx.x * 1024 + t * 4;
  int v[4];
#pragma unroll
  for (int j = 0; j < 4; ++j) {
    const int i = base + j;
    v[j] = (i < n) ? cnt[i] : 0;
    if (i < n) dinv[i] = rsqrtf((float)(v[j] + 1));
  }
  const int s4 = v[0] + v[1] + v[2] + v[3];
  sdata[t] = s4;
  __syncthreads();
  for (int off = 1; off < 256; off <<= 1) {
    int val = 0;
    if (t >= off) val = sdata[t - off];
    __syncthreads();
    sdata[t] += val;
    __syncthreads();
  }
  int run = sdata[t] - s4;  // exclusive prefix of this thread's 4 items
#pragma unroll
  for (int j = 0; j < 4; ++j) {
    const int i = base + j;
    if (i < n) excl[i] = run;
    run += v[j];
  }
  if (t == 255) bsums[blockIdx.x] = sdata[255];
}

__global__ __launch_bounds__(256) void k_scanB(int* __restrict__ bsums, int nb) {
  __shared__ int sdata[256];
  const int t = threadIdx.x;
  const int v = (t < nb) ? bsums[t] : 0;
  sdata[t] = v;
  __syncthreads();
  for (int off = 1; off < 256; off <<= 1) {
    int val = 0;
    if (t >= off) val = sdata[t - off];
    __syncthreads();
    sdata[t] += val;
    __syncthreads();
  }
  if (t < nb) bsums[t] = sdata[t] - v;  // exclusive, in place
}

__global__ __launch_bounds__(256) void k_scanC(int* __restrict__ rowptr, const int* __restrict__ boff,
                                               int n, int n_edges) {
  const int i = blockIdx.x * 256 + threadIdx.x;
  if (i < n) rowptr[i] += boff[i >> 10];
  if (i == 0) rowptr[n] = n_edges;
}

// pure gather + single scattered 4B write per edge (no atomics here).
__global__ __launch_bounds__(256) void k_fill(const int* __restrict__ src, const int* __restrict__ dst,
                                              const int* __restrict__ rank, const int* __restrict__ rowptr,
                                              int* __restrict__ csr_src, int n_edges) {
  const int e = blockIdx.x * 256 + threadIdx.x;
  if (e >= n_edges) return;
  const int d = dst[e];
  const int pos = rowptr[d] + rank[e];
  csr_src[pos] = src[e];
}

// ---------------- GEMM 1: thread = node, software-pipelined x loads ----------------
// W indices depend only on loop counters -> s_load (SGPR broadcast). The x row
// (128 float4 per thread) is the latency chain; prefetch the next 4 float4 into
// registers before the 640-FMA consume block (1280 cyc >> HBM latency).
// Deterministic, register-only — identical summation order to the R2 kernel.

__device__ __forceinline__ void consume16(float acc[CHID], const float4 cur[4],
                                          const float* __restrict__ Wb) {
#pragma unroll
  for (int j = 0; j < 4; ++j) {
    const float4 xv = cur[j];
    const float* __restrict__ Wk = Wb + j * 4 * CHID;
#pragma unroll
    for (int c = 0; c < CHID; ++c) {
      float a = acc[c];
      a = fmaf(xv.x, Wk[c], a);
      a = fmaf(xv.y, Wk[CHID + c], a);
      a = fmaf(xv.z, Wk[2 * CHID + c], a);
      a = fmaf(xv.w, Wk[3 * CHID + c], a);
      acc[c] = a;
    }
  }
}

__global__ __launch_bounds__(64) void k_gemm1(const float* __restrict__ x, const float* __restrict__ W,
                                              float* __restrict__ h, int n) {
  const int node = blockIdx.x * 64 + threadIdx.x;
  if (node >= n) return;
  const float4* __restrict__ x4 = (const float4*)(x + (size_t)node * CIN);
  float acc[CHID];
#pragma unroll
  for (int c = 0; c < CHID; ++c) acc[c] = 0.f;

  float4 cur[4], nxt[4];
#pragma unroll
  for (int j = 0; j < 4; ++j) cur[j] = x4[j];
  for (int b = 0; b < 31; ++b) {  // 32 batches of 4 float4 (16 k-values each)
#pragma unroll
    for (int j = 0; j < 4; ++j) nxt[j] = x4[(b + 1) * 4 + j];
    consume16(acc, cur, W + b * 16 * CHID);
#pragma unroll
    for (int j = 0; j < 4; ++j) cur[j] = nxt[j];
  }
  consume16(acc, cur, W + 31 * 16 * CHID);

  float* __restrict__ o = h + (size_t)node * CHID;
#pragma unroll
  for (int c = 0; c < CHID; ++c) o[c] = acc[c];
}

__global__ __launch_bounds__(256) void k_gemm2(const float* __restrict__ t1, const float* __restrict__ W,
                                               float* __restrict__ g, int n) {
  const int node = blockIdx.x * 256 + threadIdx.x;
  if (node >= n) return;
  const float4* __restrict__ r4 = (const float4*)(t1 + (size_t)node * CHID);
  float acc[COUT];
#pragma unroll
  for (int c = 0; c < COUT; ++c) acc[c] = 0.f;
#pragma unroll
  for (int kk = 0; kk < CHID / 4; ++kk) {
    const float4 xv = r4[kk];
    const float* __restrict__ Wk = W + kk * 4 * COUT;
#pragma unroll
    for (int c = 0; c < COUT; ++c) {
      float a = acc[c];
      a = fmaf(xv.x, Wk[c], a);
      a = fmaf(xv.y, Wk[COUT + c], a);
      a = fmaf(xv.z, Wk[2 * COUT + c], a);
      a = fmaf(xv.w, Wk[3 * COUT + c], a);
      acc[c] = a;
    }
  }
  float* __restrict__ o = g + (size_t)node * COUT;
#pragma unroll
  for (int c = 0; c < COUT; ++c) o[c] = acc[c];
}

// ---------------- CSR aggregation ----------------
// Layer 1 (CH=40): one wave per node, lanes 0..39 = channels. csr_src + dinv
// loads are wave-uniform -> scalar load chain; weight computed on the fly.
__global__ __launch_bounds__(256) void k_agg40(const float* __restrict__ h, const int* __restrict__ rowptr,
                                               const int* __restrict__ csr_src, const float* __restrict__ dinv,
                                               const float* __restrict__ bias, float* __restrict__ out, int n) {
  const int wid = (blockIdx.x * 256 + (int)threadIdx.x) >> 6;
  const int lane = threadIdx.x & 63;
  if (wid >= n) return;
  const int node = __builtin_amdgcn_readfirstlane(wid);
  const int r0 = rowptr[node];
  const int r1 = rowptr[node + 1];
  const float dv = dinv[node];
  const float self_w = dv * dv;  // self-loop norm = 1/deg
  const bool act = lane < CHID;
  float acc = 0.f;
  if (act) acc = h[(size_t)node * CHID + lane] * self_w;
  int i = r0;
  for (; i + 4 <= r1; i += 4) {
    const int s0 = csr_src[i + 0];
    const int s1 = csr_src[i + 1];
    const int s2 = csr_src[i + 2];
    const int s3 = csr_src[i + 3];
    const float w0 = dinv[s0] * dv;
    const float w1 = dinv[s1] * dv;
    const float w2 = dinv[s2] * dv;
    const float w3 = dinv[s3] * dv;
    if (act) {
      const float g0 = h[(size_t)s0 * CHID + lane];
      const float g1 = h[(size_t)s1 * CHID + lane];
      const float g2 = h[(size_t)s2 * CHID + lane];
      const float g3 = h[(size_t)s3 * CHID + lane];
      acc = fmaf(g0, w0, acc);
      acc = fmaf(g1, w1, acc);
      acc = fmaf(g2, w2, acc);
      acc = fmaf(g3, w3, acc);
    }
  }
  for (; i < r1; ++i) {
    const int s = csr_src[i];
    const float w = dinv[s] * dv;
    if (act) acc = fmaf(h[(size_t)s * CHID + lane], w, acc);
  }
  if (act) {
    float v = acc + bias[lane];
    v = fmaxf(v, 0.f);  // ReLU (layer 1 only)
    out[(size_t)node * CHID + lane] = v;
  }
}

// Layer 2 (CH=20): 3 nodes per wave (lanes 0..59), per-lane loop with exec-mask
// divergence across the 3 subgroups; loads within a subgroup coalesce/broadcast.
__global__ __launch_bounds__(256) void k_agg20(const float* __restrict__ h, const int* __restrict__ rowptr,
                                               const int* __restrict__ csr_src, const float* __restrict__ dinv,
                                               const float* __restrict__ bias, float* __restrict__ out, int n) {
  const int wave = (blockIdx.x * 256 + (int)threadIdx.x) >> 6;
  const int lane = threadIdx.x & 63;
  const int sub = lane / COUT;   // 0..2 active, 3 => idle lanes 60..63
  const int ch = lane % COUT;
  const int node = wave * 3 + sub;
  if (sub >= 3 || node >= n) return;
  const int r0 = rowptr[node];
  const int r1 = rowptr[node + 1];
  const float dv = dinv[node];
  float acc = h[(size_t)node * COUT + ch] * (dv * dv);
  int i = r0;
  for (; i + 2 <= r1; i += 2) {
    const int s0 = csr_src[i + 0];
    const int s1 = csr_src[i + 1];
    const float w0 = dinv[s0] * dv;
    const float w1 = dinv[s1] * dv;
    acc = fmaf(h[(size_t)s0 * COUT + ch], w0, acc);
    acc = fmaf(h[(size_t)s1 * COUT + ch], w1, acc);
  }
  if (i < r1) {
    const int s = csr_src[i];
    acc = fmaf(h[(size_t)s * COUT + ch], dinv[s] * dv, acc);
  }
  out[(size_t)node * COUT + ch] = acc + bias[ch];
}

// ---------------- launch ----------------

extern "C" void kernel_launch(void* const* d_in, const int* in_sizes, int n_in,
                              void* d_out, int out_size, void* d_ws, size_t ws_size,
                              hipStream_t stream) {
  const float* x   = (const float*)d_in[0];
  const int*   ei  = (const int*)d_in[1];
  const float* W1  = (const float*)d_in[2];
  const float* b1  = (const float*)d_in[3];
  const float* W2  = (const float*)d_in[4];
  const float* b2  = (const float*)d_in[5];
  float* out = (float*)d_out;

  const int* srcp = ei;        // edge_index[0]
  const int* dstp = ei + NE;   // edge_index[1]

  // workspace layout (~59 MB)
  char* ws = (char*)d_ws;
  size_t off = 0;
  auto take = [&](size_t bytes) -> char* {
    char* p = ws + off;
    off = (off + bytes + 255) & ~(size_t)255;
    return p;
  };
  int*   cnt     = (int*)take((size_t)NN * 4);
  int*   rowptr  = (int*)take((size_t)(NN + 1) * 4);
  float* dinv    = (float*)take((size_t)NN * 4);
  int*   bsums   = (int*)take(256 * 4);
  int*   rank    = (int*)take((size_t)NE * 4);
  int*   csr_src = (int*)take((size_t)NE * 4);
  float* h1      = (float*)take((size_t)NN * CHID * 4);
  float* t1      = (float*)take((size_t)NN * CHID * 4);
  float* g2      = h1;  // h1 dead after agg1; reuse for layer-2 GEMM output

  (void)in_sizes; (void)n_in; (void)out_size; (void)ws_size;

  hipMemsetAsync(cnt, 0, (size_t)NN * 4, stream);

  k_count<<<(NE + 255) / 256, 256, 0, stream>>>(dstp, cnt, rank, NE);
  const int nb = (NN + 1023) / 1024;  // 98
  k_scanA<<<nb, 256, 0, stream>>>(cnt, rowptr, bsums, dinv, NN);
  k_scanB<<<1, 256, 0, stream>>>(bsums, nb);
  k_scanC<<<(NN + 255) / 256, 256, 0, stream>>>(rowptr, bsums, NN, NE);
  k_fill<<<(NE + 255) / 256, 256, 0, stream>>>(srcp, dstp, rank, rowptr, csr_src, NE);

  k_gemm1<<<(NN + 63) / 64, 64, 0, stream>>>(x, W1, h1, NN);
  k_agg40<<<(NN + 3) / 4, 256, 0, stream>>>(h1, rowptr, csr_src, dinv, b1, t1, NN);
  k_gemm2<<<(NN + 255) / 256, 256, 0, stream>>>(t1, W2, g2, NN);
  const int nwaves2 = (NN + 2) / 3;
  k_agg20<<<(nwaves2 + 3) / 4, 256, 0, stream>>>(g2, rowptr, csr_src, dinv, b2, out, NN);
}